// Round 1
// baseline (55.020 us; speedup 1.0000x reference)
//
#include <hip/hip_runtime.h>

// Problem constants (fixed-shape problem)
#define NBATCH 4
#define NPTS   8192          // source points per batch
#define MTGT   8192          // target points per batch
#define BN     (NBATCH*NPTS) // 32768 total source points
#define CHUNK  1024          // targets staged per block
#define NCHUNK (MTGT/CHUNK)  // 8
#define TPB    256

// Monotone float->uint key: preserves float ordering under unsigned compare.
__device__ __forceinline__ unsigned f2key(float x) {
    unsigned u = __float_as_uint(x);
    return (u & 0x80000000u) ? ~u : (u | 0x80000000u);
}
__device__ __forceinline__ float key2f(unsigned k) {
    return __uint_as_float((k & 0x80000000u) ? (k ^ 0x80000000u) : ~k);
}

__global__ __launch_bounds__(256) void init_kernel(unsigned* __restrict__ wsmin) {
    int i = blockIdx.x * 256 + threadIdx.x;
    if (i < BN) wsmin[i] = 0xFFFFFFFFu;  // key-space +infinity
}

// Phase 1: per source point, partial min over one chunk of targets of
//   d' = ||t||^2 - 2 s.t    (exact distance = d' + ||s||^2, added later)
__global__ __launch_bounds__(TPB) void nn_min_kernel(const float* __restrict__ src,
                                                     const float* __restrict__ tgt,
                                                     unsigned* __restrict__ wsmin) {
    __shared__ float4 lt[CHUNK];  // (x, y, z, ||t||^2) ; invalid -> w = 1e30

    const int tid  = threadIdx.x;
    const int gid  = blockIdx.x * TPB + tid;   // source index in [0, BN)
    const int b    = gid / NPTS;               // batch (uniform within block)
    const int c    = blockIdx.y;               // target chunk

    // ---- stage CHUNK targets: 4 per thread, AoS float3 -> float4 with t_sq ----
    const float4* tv = reinterpret_cast<const float4*>(
        tgt + ((size_t)b * MTGT + (size_t)c * CHUNK) * 3);
    float4 a0 = tv[3 * tid + 0];
    float4 a1 = tv[3 * tid + 1];
    float4 a2 = tv[3 * tid + 2];

    float px[4] = {a0.x, a0.w, a1.z, a2.y};
    float py[4] = {a0.y, a1.x, a1.w, a2.z};
    float pz[4] = {a0.z, a1.y, a2.x, a2.w};
#pragma unroll
    for (int j = 0; j < 4; ++j) {
        float x = px[j], y = py[j], z = pz[j];
        float tsq = fmaf(x, x, fmaf(y, y, z * z));
        bool valid = (x != 0.f) || (y != 0.f) || (z != 0.f);
        lt[4 * tid + j] = make_float4(x, y, z, valid ? tsq : 1e30f);
    }
    __syncthreads();

    // ---- inner loop: 3 FMA + 1 min per target ----
    float sx = src[(size_t)gid * 3 + 0];
    float sy = src[(size_t)gid * 3 + 1];
    float sz = src[(size_t)gid * 3 + 2];
    float ax = -2.f * sx, ay = -2.f * sy, az = -2.f * sz;

    float b0 = 3e38f, b1 = 3e38f, b2 = 3e38f, b3 = 3e38f;
#pragma unroll 2
    for (int m = 0; m < CHUNK; m += 4) {
        float4 t0 = lt[m + 0];
        float4 t1 = lt[m + 1];
        float4 t2 = lt[m + 2];
        float4 t3 = lt[m + 3];
        b0 = fminf(b0, fmaf(ax, t0.x, fmaf(ay, t0.y, fmaf(az, t0.z, t0.w))));
        b1 = fminf(b1, fmaf(ax, t1.x, fmaf(ay, t1.y, fmaf(az, t1.z, t1.w))));
        b2 = fminf(b2, fmaf(ax, t2.x, fmaf(ay, t2.y, fmaf(az, t2.z, t2.w))));
        b3 = fminf(b3, fmaf(ax, t3.x, fmaf(ay, t3.y, fmaf(az, t3.z, t3.w))));
    }
    float best = fminf(fminf(b0, b1), fminf(b2, b3));

    atomicMin(&wsmin[gid], f2key(best));
}

// Phase 2: per-batch weighted mean of exact squared distances.
__global__ __launch_bounds__(256) void reduce_kernel(const float* __restrict__ src,
                                                     const unsigned* __restrict__ wsmin,
                                                     float* __restrict__ batch_out) {
    const int b = blockIdx.x;
    const int tid = threadIdx.x;
    double sum = 0.0, cnt = 0.0;
    for (int n = tid; n < NPTS; n += 256) {
        int gid = b * NPTS + n;
        float sx = src[(size_t)gid * 3 + 0];
        float sy = src[(size_t)gid * 3 + 1];
        float sz = src[(size_t)gid * 3 + 2];
        bool valid = (sx != 0.f) || (sy != 0.f) || (sz != 0.f);
        float ssq = fmaf(sx, sx, fmaf(sy, sy, sz * sz));
        float sq = fmaxf(0.f, ssq + key2f(wsmin[gid]));
        if (valid) { sum += (double)sq; cnt += 1.0; }
    }
    __shared__ double sh[512];
    sh[tid] = sum; sh[256 + tid] = cnt;
    __syncthreads();
    for (int s = 128; s > 0; s >>= 1) {
        if (tid < s) { sh[tid] += sh[tid + s]; sh[256 + tid] += sh[256 + tid + s]; }
        __syncthreads();
    }
    if (tid == 0) {
        double c = sh[256] > 1.0 ? sh[256] : 1.0;
        batch_out[b] = (float)(sh[0] / (3.0 * c));
    }
}

__global__ void final_kernel(const float* __restrict__ batch_out, float* __restrict__ out) {
    out[0] = (batch_out[0] + batch_out[1] + batch_out[2] + batch_out[3]) * 0.25f;
}

extern "C" void kernel_launch(void* const* d_in, const int* in_sizes, int n_in,
                              void* d_out, int out_size, void* d_ws, size_t ws_size,
                              hipStream_t stream) {
    const float* src = (const float*)d_in[0];
    const float* tgt = (const float*)d_in[1];
    float* out = (float*)d_out;

    unsigned* wsmin   = (unsigned*)d_ws;
    float* batch_out  = (float*)((char*)d_ws + (size_t)BN * sizeof(unsigned));

    init_kernel<<<dim3(BN / 256), dim3(256), 0, stream>>>(wsmin);

    dim3 g1(BN / TPB, NCHUNK);
    nn_min_kernel<<<g1, dim3(TPB), 0, stream>>>(src, tgt, wsmin);

    reduce_kernel<<<dim3(NBATCH), dim3(256), 0, stream>>>(src, wsmin, batch_out);
    final_kernel<<<dim3(1), dim3(1), 0, stream>>>(batch_out, out);
}